// Round 1
// baseline (99.783 us; speedup 1.0000x reference)
//
#include <hip/hip_runtime.h>
#include <hip/hip_bf16.h>

#define NP     64     // partitions
#define D_IN   1024
#define RANK   64
#define D_OUT  1024
#define NTOK   4096
#define TM     64     // tokens per tile
#define BK     64     // K chunk for step 1
#define NCHUNK 256    // D_OUT chunk for step 2
#define LDSTR  72     // LDS row stride in bf16 elements (144B, 16B-aligned, bank-spread)
#define MAXTILES 128

typedef __bf16 bf16x8 __attribute__((ext_vector_type(8)));
typedef float  f32x4  __attribute__((ext_vector_type(4)));

__device__ __forceinline__ unsigned short f2bf(float f) {
    unsigned u = __builtin_bit_cast(unsigned, f);
    u += 0x7FFFu + ((u >> 16) & 1u);   // round-to-nearest-even
    return (unsigned short)(u >> 16);
}

// ---------------------------------------------------------------------------
// Kernel 1: bucket tokens by pid, build tile worklist in workspace.
// meta layout (ints): [0]=n_tiles, [16..143]=tile_pid, [144..271]=tile_off,
//                     [272..399]=tile_len, [512..512+NTOK)=bucket (token ids)
// ---------------------------------------------------------------------------
__global__ void bucket_kernel(const int* __restrict__ pids, int* __restrict__ meta) {
    __shared__ int counts[NP];
    __shared__ int cursor[NP];
    int tid = threadIdx.x;
    if (tid < NP) counts[tid] = 0;
    __syncthreads();
    for (int i = tid; i < NTOK; i += 256)
        atomicAdd(&counts[pids[i] & (NP - 1)], 1);
    __syncthreads();
    if (tid == 0) {
        int acc = 0, nt = 0;
        for (int p = 0; p < NP; ++p) {
            int c = counts[p];
            cursor[p] = acc;
            for (int t = 0; t < c; t += TM) {
                meta[16 + nt]  = p;
                meta[144 + nt] = acc + t;
                meta[272 + nt] = (c - t < TM) ? (c - t) : TM;
                ++nt;
            }
            acc += c;
        }
        meta[0] = nt;
    }
    __syncthreads();
    int* bucket = meta + 512;
    for (int i = tid; i < NTOK; i += 256) {
        int p = pids[i] & (NP - 1);
        int pos = atomicAdd(&cursor[p], 1);
        bucket[pos] = i;
    }
}

// ---------------------------------------------------------------------------
// Kernel 2: per tile (partition p, <=64 tokens):
//   H = Xtile @ U[p]   (64x1024 @ 1024x64, MFMA 16x16x32 bf16, K-chunked)
//   O = H @ V[p] + bias (64x64 @ 64x1024, D_OUT-chunked), scatter rows to out
// ---------------------------------------------------------------------------
__global__ __launch_bounds__(256, 2) void ffn_kernel(
    const float* __restrict__ x, const float* __restrict__ U,
    const float* __restrict__ V, const float* __restrict__ bias,
    const int* __restrict__ meta, float* __restrict__ out)
{
    __shared__ __align__(16) unsigned short Xs[TM][LDSTR];     // A operand, [token][k]
    __shared__ __align__(16) unsigned short Us[RANK][LDSTR];   // B^T, [r][k]
    __shared__ __align__(16) unsigned short Hs[TM][LDSTR];     // A operand step2, [token][r]
    __shared__ __align__(16) unsigned short Vs[NCHUNK][LDSTR]; // B^T step2, [o][r]
    __shared__ int toks[TM];

    int nt = meta[0];
    int b = blockIdx.x;
    if (b >= nt) return;
    int p   = meta[16 + b];
    int off = meta[144 + b];
    int len = meta[272 + b];

    int tid  = threadIdx.x;
    int lane = tid & 63;
    int w    = tid >> 6;
    int l15  = lane & 15;
    int l4   = lane >> 4;

    const int* bucket = meta + 512;
    if (tid < TM) toks[tid] = (tid < len) ? bucket[off + tid] : -1;
    __syncthreads();

    const float* Up = U + (size_t)p * D_IN * RANK;
    const float* Vp = V + (size_t)p * RANK * D_OUT;

    // ---- step 1: H = X @ U[p] ----
    int wr = (w & 1) * 32;   // wave row offset in 64x64 H
    int wc = (w >> 1) * 32;  // wave col offset
    f32x4 acc[2][2] = {};

    int xr = tid >> 2;          // 0..63 token row for X staging
    int xq = (tid & 3) * 16;    // k quarter

    for (int kc = 0; kc < D_IN; kc += BK) {
        // stage X rows (gather by token), fp32 -> bf16
        {
            int t = toks[xr];
            const float* xp = x + (size_t)((t >= 0) ? t : 0) * D_IN + kc + xq;
#pragma unroll
            for (int i = 0; i < 4; ++i) {
                float4 v;
                if (t >= 0) v = *reinterpret_cast<const float4*>(xp + i * 4);
                else        v = float4{0.f, 0.f, 0.f, 0.f};
                int k = xq + i * 4;
                Xs[xr][k + 0] = f2bf(v.x);
                Xs[xr][k + 1] = f2bf(v.y);
                Xs[xr][k + 2] = f2bf(v.z);
                Xs[xr][k + 3] = f2bf(v.w);
            }
        }
        // stage U transposed: Us[r][kk] = U[p][kc+kk][r] (global reads coalesced over r)
        {
            int r  = tid & 63;
            int kb = tid >> 6;  // 0..3
#pragma unroll
            for (int pass = 0; pass < 16; ++pass) {
                int kk = pass * 4 + kb;
                Us[r][kk] = f2bf(Up[(size_t)(kc + kk) * RANK + r]);
            }
        }
        __syncthreads();
#pragma unroll
        for (int ks = 0; ks < 2; ++ks) {
            int kof = ks * 32 + l4 * 8;
            bf16x8 a0 = *reinterpret_cast<const bf16x8*>(&Xs[wr + l15][kof]);
            bf16x8 a1 = *reinterpret_cast<const bf16x8*>(&Xs[wr + 16 + l15][kof]);
            bf16x8 b0 = *reinterpret_cast<const bf16x8*>(&Us[wc + l15][kof]);
            bf16x8 b1 = *reinterpret_cast<const bf16x8*>(&Us[wc + 16 + l15][kof]);
            acc[0][0] = __builtin_amdgcn_mfma_f32_16x16x32_bf16(a0, b0, acc[0][0], 0, 0, 0);
            acc[0][1] = __builtin_amdgcn_mfma_f32_16x16x32_bf16(a0, b1, acc[0][1], 0, 0, 0);
            acc[1][0] = __builtin_amdgcn_mfma_f32_16x16x32_bf16(a1, b0, acc[1][0], 0, 0, 0);
            acc[1][1] = __builtin_amdgcn_mfma_f32_16x16x32_bf16(a1, b1, acc[1][1], 0, 0, 0);
        }
        __syncthreads();
    }

    // write H (bf16) to LDS; C/D layout: col=lane&15, row=(lane>>4)*4+reg
#pragma unroll
    for (int mi = 0; mi < 2; ++mi)
#pragma unroll
        for (int ni = 0; ni < 2; ++ni)
#pragma unroll
            for (int j = 0; j < 4; ++j) {
                int row = wr + mi * 16 + l4 * 4 + j;
                int col = wc + ni * 16 + l15;
                Hs[row][col] = f2bf(acc[mi][ni][j]);
            }
    __syncthreads();

    // ---- step 2: O = H @ V[p] + bias, chunked over D_OUT ----
    int wr2 = (w & 1) * 32;    // rows within 64
    int wc2 = (w >> 1) * 128;  // cols within NCHUNK

    for (int oc = 0; oc < D_OUT; oc += NCHUNK) {
        // stage V transposed: Vs[o][r] = V[p][r][oc+o] (float4 over o, coalesced)
        {
            int o4 = (tid & 63) * 4;
            int rb = tid >> 6;  // 0..3
#pragma unroll
            for (int pass = 0; pass < 16; ++pass) {
                int r = pass * 4 + rb;
                float4 v = *reinterpret_cast<const float4*>(&Vp[(size_t)r * D_OUT + oc + o4]);
                Vs[o4 + 0][r] = f2bf(v.x);
                Vs[o4 + 1][r] = f2bf(v.y);
                Vs[o4 + 2][r] = f2bf(v.z);
                Vs[o4 + 3][r] = f2bf(v.w);
            }
        }
        __syncthreads();

        f32x4 acc2[2][8] = {};
#pragma unroll
        for (int ks = 0; ks < 2; ++ks) {
            int kof = ks * 32 + l4 * 8;
            bf16x8 a0 = *reinterpret_cast<const bf16x8*>(&Hs[wr2 + l15][kof]);
            bf16x8 a1 = *reinterpret_cast<const bf16x8*>(&Hs[wr2 + 16 + l15][kof]);
#pragma unroll
            for (int ni = 0; ni < 8; ++ni) {
                bf16x8 bb = *reinterpret_cast<const bf16x8*>(&Vs[wc2 + ni * 16 + l15][kof]);
                acc2[0][ni] = __builtin_amdgcn_mfma_f32_16x16x32_bf16(a0, bb, acc2[0][ni], 0, 0, 0);
                acc2[1][ni] = __builtin_amdgcn_mfma_f32_16x16x32_bf16(a1, bb, acc2[1][ni], 0, 0, 0);
            }
        }

        // bias + scatter store (fp32 out)
#pragma unroll
        for (int ni = 0; ni < 8; ++ni) {
            int col = oc + wc2 + ni * 16 + l15;
            float bv = bias[col];
#pragma unroll
            for (int mi = 0; mi < 2; ++mi)
#pragma unroll
                for (int j = 0; j < 4; ++j) {
                    int row = wr2 + mi * 16 + l4 * 4 + j;
                    if (row < len)
                        out[(size_t)toks[row] * D_OUT + col] = acc2[mi][ni][j] + bv;
                }
        }
        __syncthreads();  // before overwriting Vs next chunk
    }
}

extern "C" void kernel_launch(void* const* d_in, const int* in_sizes, int n_in,
                              void* d_out, int out_size, void* d_ws, size_t ws_size,
                              hipStream_t stream) {
    const float* x    = (const float*)d_in[0];
    const int*   pids = (const int*)d_in[1];
    const float* U    = (const float*)d_in[2];
    const float* V    = (const float*)d_in[3];
    const float* bias = (const float*)d_in[4];
    float* out = (float*)d_out;
    int* meta = (int*)d_ws;

    bucket_kernel<<<1, 256, 0, stream>>>(pids, meta);
    ffn_kernel<<<MAXTILES, 256, 0, stream>>>(x, U, V, bias, meta, out);
}

// Round 2
// 58.361 us; speedup vs baseline: 1.7097x; 1.7097x over previous
//
#include <hip/hip_runtime.h>
#include <hip/hip_bf16.h>

#define NP     64     // partitions
#define D_IN   1024
#define RANK   64
#define D_OUT  1024
#define NTOK   4096
#define TM     64     // tokens per tile
#define BK     64     // K chunk for step 1
#define MT     128    // max tiles (worst case 127)
#define OSPLIT 8      // D_OUT split for o_kernel
#define OW     128    // D_OUT cols per o-block
#define LDSTR  72     // LDS row stride in bf16 elems (144B, 16B-aligned, bank-spread)

typedef __bf16 bf16x8 __attribute__((ext_vector_type(8)));
typedef float  f32x4  __attribute__((ext_vector_type(4)));

__device__ __forceinline__ unsigned short f2bf(float f) {
    unsigned u = __builtin_bit_cast(unsigned, f);
    u += 0x7FFFu + ((u >> 16) & 1u);   // round-to-nearest-even
    return (unsigned short)(u >> 16);
}

// ---------------------------------------------------------------------------
// Kernel 1: bucket tokens by pid, build tile worklist in workspace.
// meta layout (ints): [0]=n_tiles, [16..143]=tile_pid, [144..271]=tile_off,
//                     [272..399]=tile_len, [512..512+NTOK)=bucket (token ids)
// ---------------------------------------------------------------------------
__global__ void bucket_kernel(const int* __restrict__ pids, int* __restrict__ meta) {
    __shared__ int counts[NP];
    __shared__ int cursor[NP];
    int tid = threadIdx.x;
    if (tid < NP) counts[tid] = 0;
    __syncthreads();
    for (int i = tid; i < NTOK; i += 256)
        atomicAdd(&counts[pids[i] & (NP - 1)], 1);
    __syncthreads();
    if (tid == 0) {
        int acc = 0, nt = 0;
        for (int p = 0; p < NP; ++p) {
            int c = counts[p];
            cursor[p] = acc;
            for (int t = 0; t < c; t += TM) {
                meta[16 + nt]  = p;
                meta[144 + nt] = acc + t;
                meta[272 + nt] = (c - t < TM) ? (c - t) : TM;
                ++nt;
            }
            acc += c;
        }
        meta[0] = nt;
    }
    __syncthreads();
    int* bucket = meta + 512;
    for (int i = tid; i < NTOK; i += 256) {
        int p = pids[i] & (NP - 1);
        int pos = atomicAdd(&cursor[p], 1);
        bucket[pos] = i;
    }
}

// ---------------------------------------------------------------------------
// Kernel 2: partial H. grid = nt * ksplit blocks; block (tile, ks) computes
// Hpart[ks][tile] (64x64 fp32) = Xtile[:, ks*kw:(ks+1)*kw] @ U[p][slice]
// ---------------------------------------------------------------------------
__global__ __launch_bounds__(256, 4) void h_kernel(
    const float* __restrict__ x, const float* __restrict__ U,
    const int* __restrict__ meta, float* __restrict__ Hpart, int kslog2)
{
    __shared__ __align__(16) unsigned short Xs[TM][LDSTR];
    __shared__ __align__(16) unsigned short Us[RANK][LDSTR];
    __shared__ int toks[TM];

    int ksplit = 1 << kslog2;
    int tile = blockIdx.x >> kslog2;
    int ks   = blockIdx.x & (ksplit - 1);
    int nt = meta[0];
    if (tile >= nt) return;
    int p   = meta[16 + tile];
    int off = meta[144 + tile];
    int len = meta[272 + tile];

    int tid  = threadIdx.x;
    int lane = tid & 63;
    int w    = tid >> 6;
    int l15  = lane & 15;
    int l4   = lane >> 4;

    const int* bucket = meta + 512;
    if (tid < TM) toks[tid] = (tid < len) ? bucket[off + tid] : -1;
    __syncthreads();

    const float* Up = U + (size_t)p * D_IN * RANK;

    int wr = (w & 1) * 32;
    int wc = (w >> 1) * 32;
    f32x4 acc[2][2] = {};

    int xr = tid >> 2;          // token row for X staging
    int xq = (tid & 3) * 16;    // k quarter within BK

    int kw = D_IN >> kslog2;
    int kbeg = ks * kw, kend = kbeg + kw;

    for (int kc = kbeg; kc < kend; kc += BK) {
        // stage X rows (gather by token), fp32 -> bf16
        {
            int t = toks[xr];
            const float* xp = x + (size_t)((t >= 0) ? t : 0) * D_IN + kc + xq;
#pragma unroll
            for (int i = 0; i < 4; ++i) {
                float4 v;
                if (t >= 0) v = *reinterpret_cast<const float4*>(xp + i * 4);
                else        v = float4{0.f, 0.f, 0.f, 0.f};
                int k = xq + i * 4;
                Xs[xr][k + 0] = f2bf(v.x);
                Xs[xr][k + 1] = f2bf(v.y);
                Xs[xr][k + 2] = f2bf(v.z);
                Xs[xr][k + 3] = f2bf(v.w);
            }
        }
        // stage U transposed with float4 loads: Us[r][kk] = U[p][kc+kk][r]
        {
            int kk = tid >> 2;          // 0..63
            int q  = (tid & 3) * 16;    // r quarter
            const float* up = Up + (size_t)(kc + kk) * RANK + q;
#pragma unroll
            for (int i = 0; i < 4; ++i) {
                float4 v = *reinterpret_cast<const float4*>(up + i * 4);
                int r = q + i * 4;
                Us[r + 0][kk] = f2bf(v.x);
                Us[r + 1][kk] = f2bf(v.y);
                Us[r + 2][kk] = f2bf(v.z);
                Us[r + 3][kk] = f2bf(v.w);
            }
        }
        __syncthreads();
#pragma unroll
        for (int k2 = 0; k2 < 2; ++k2) {
            int kof = k2 * 32 + l4 * 8;
            bf16x8 a0 = *reinterpret_cast<const bf16x8*>(&Xs[wr + l15][kof]);
            bf16x8 a1 = *reinterpret_cast<const bf16x8*>(&Xs[wr + 16 + l15][kof]);
            bf16x8 b0 = *reinterpret_cast<const bf16x8*>(&Us[wc + l15][kof]);
            bf16x8 b1 = *reinterpret_cast<const bf16x8*>(&Us[wc + 16 + l15][kof]);
            acc[0][0] = __builtin_amdgcn_mfma_f32_16x16x32_bf16(a0, b0, acc[0][0], 0, 0, 0);
            acc[0][1] = __builtin_amdgcn_mfma_f32_16x16x32_bf16(a0, b1, acc[0][1], 0, 0, 0);
            acc[1][0] = __builtin_amdgcn_mfma_f32_16x16x32_bf16(a1, b0, acc[1][0], 0, 0, 0);
            acc[1][1] = __builtin_amdgcn_mfma_f32_16x16x32_bf16(a1, b1, acc[1][1], 0, 0, 0);
        }
        __syncthreads();
    }

    // write partial H fp32: C/D layout col=lane&15, row=(lane>>4)*4+reg
    float* hp = Hpart + ((size_t)ks * MT + tile) * (TM * RANK);
#pragma unroll
    for (int mi = 0; mi < 2; ++mi)
#pragma unroll
        for (int ni = 0; ni < 2; ++ni)
#pragma unroll
            for (int j = 0; j < 4; ++j) {
                int row = wr + mi * 16 + l4 * 4 + j;
                int col = wc + ni * 16 + l15;
                hp[row * RANK + col] = acc[mi][ni][j];
            }
}

// ---------------------------------------------------------------------------
// Kernel 3: O = H @ V[p] + bias for one (tile, 128-col chunk).
// grid = nt * OSPLIT blocks.
// ---------------------------------------------------------------------------
__global__ __launch_bounds__(256, 4) void o_kernel(
    const float* __restrict__ V, const float* __restrict__ bias,
    const int* __restrict__ meta, const float* __restrict__ Hpart,
    float* __restrict__ out, int ksplit)
{
    __shared__ __align__(16) unsigned short Hs[TM][LDSTR];
    __shared__ __align__(16) unsigned short Vs[OW][LDSTR];
    __shared__ int toks[TM];

    int tile = blockIdx.x >> 3;   // OSPLIT = 8
    int oc   = (blockIdx.x & 7) * OW;
    int nt = meta[0];
    if (tile >= nt) return;
    int p   = meta[16 + tile];
    int off = meta[144 + tile];
    int len = meta[272 + tile];

    int tid  = threadIdx.x;
    int lane = tid & 63;
    int w    = tid >> 6;
    int l15  = lane & 15;
    int l4   = lane >> 4;

    const int* bucket = meta + 512;
    if (tid < TM) toks[tid] = (tid < len) ? bucket[off + tid] : -1;

    // sum partial H (fp32) -> bf16 Hs
#pragma unroll
    for (int j = 0; j < 4; ++j) {
        int e = (j * 256 + tid) * 4;
        float4 s = float4{0.f, 0.f, 0.f, 0.f};
        for (int k = 0; k < ksplit; ++k) {
            float4 v = *reinterpret_cast<const float4*>(
                &Hpart[((size_t)k * MT + tile) * (TM * RANK) + e]);
            s.x += v.x; s.y += v.y; s.z += v.z; s.w += v.w;
        }
        int row = e >> 6;
        int col = e & 63;
        ushort4 h;
        h.x = f2bf(s.x); h.y = f2bf(s.y); h.z = f2bf(s.z); h.w = f2bf(s.w);
        *reinterpret_cast<ushort4*>(&Hs[row][col]) = h;
    }

    // stage V transposed: Vs[o][r] = V[p][r][oc+o]
    const float* Vp = V + (size_t)p * RANK * D_OUT;
    {
        int o4 = (tid & 31) * 4;
        int rb = tid >> 5;          // 0..7
#pragma unroll
        for (int pass = 0; pass < 8; ++pass) {
            int r = pass * 8 + rb;
            float4 v = *reinterpret_cast<const float4*>(&Vp[(size_t)r * D_OUT + oc + o4]);
            Vs[o4 + 0][r] = f2bf(v.x);
            Vs[o4 + 1][r] = f2bf(v.y);
            Vs[o4 + 2][r] = f2bf(v.z);
            Vs[o4 + 3][r] = f2bf(v.w);
        }
    }
    __syncthreads();

    // MFMA: 64x128 output; wave (w&1) -> 32 rows, (w>>1) -> 64 cols
    int wr2 = (w & 1) * 32;
    int wc2 = (w >> 1) * 64;
    f32x4 acc2[2][4] = {};
#pragma unroll
    for (int k2 = 0; k2 < 2; ++k2) {
        int kof = k2 * 32 + l4 * 8;
        bf16x8 a0 = *reinterpret_cast<const bf16x8*>(&Hs[wr2 + l15][kof]);
        bf16x8 a1 = *reinterpret_cast<const bf16x8*>(&Hs[wr2 + 16 + l15][kof]);
#pragma unroll
        for (int ni = 0; ni < 4; ++ni) {
            bf16x8 bb = *reinterpret_cast<const bf16x8*>(&Vs[wc2 + ni * 16 + l15][kof]);
            acc2[0][ni] = __builtin_amdgcn_mfma_f32_16x16x32_bf16(a0, bb, acc2[0][ni], 0, 0, 0);
            acc2[1][ni] = __builtin_amdgcn_mfma_f32_16x16x32_bf16(a1, bb, acc2[1][ni], 0, 0, 0);
        }
    }

    // bias + scatter store
#pragma unroll
    for (int ni = 0; ni < 4; ++ni) {
        int col = oc + wc2 + ni * 16 + l15;
        float bv = bias[col];
#pragma unroll
        for (int mi = 0; mi < 2; ++mi)
#pragma unroll
            for (int j = 0; j < 4; ++j) {
                int row = wr2 + mi * 16 + l4 * 4 + j;
                if (row < len)
                    out[(size_t)toks[row] * D_OUT + col] = acc2[mi][ni][j] + bv;
            }
    }
}

extern "C" void kernel_launch(void* const* d_in, const int* in_sizes, int n_in,
                              void* d_out, int out_size, void* d_ws, size_t ws_size,
                              hipStream_t stream) {
    const float* x    = (const float*)d_in[0];
    const int*   pids = (const int*)d_in[1];
    const float* U    = (const float*)d_in[2];
    const float* V    = (const float*)d_in[3];
    const float* bias = (const float*)d_in[4];
    float* out = (float*)d_out;
    int* meta = (int*)d_ws;

    // pick largest ksplit in {4,2,1} that fits the workspace
    int kslog2 = 2;
    while (kslog2 > 0 &&
           65536 + (((size_t)MT << kslog2) * TM * RANK * 4) > ws_size)
        --kslog2;
    int ksplit = 1 << kslog2;
    float* Hpart = (float*)((char*)d_ws + 65536);

    bucket_kernel<<<1, 256, 0, stream>>>(pids, meta);
    h_kernel<<<MT * ksplit, 256, 0, stream>>>(x, U, meta, Hpart, kslog2);
    o_kernel<<<MT * OSPLIT, 256, 0, stream>>>(V, bias, meta, Hpart, out, ksplit);
}

// Round 3
// 52.227 us; speedup vs baseline: 1.9106x; 1.1175x over previous
//
#include <hip/hip_runtime.h>
#include <hip/hip_bf16.h>

#define NP     64     // partitions
#define D_IN   1024
#define RANK   64
#define D_OUT  1024
#define NTOK   4096
#define TM     64     // tokens per tile
#define BK     64     // K chunk for h step
#define MT     128    // max tiles
#define KS     8      // K-split for h_kernel
#define KW     (D_IN / KS)   // 128
#define OW     128    // D_OUT cols per o-block
#define OSPLIT (D_OUT / OW)  // 8
#define LDSTR  72     // LDS row stride in bf16 elems (144B, 16B-aligned, bank-spread)

typedef __bf16 bf16x8 __attribute__((ext_vector_type(8)));
typedef float  f32x4  __attribute__((ext_vector_type(4)));

__device__ __forceinline__ unsigned short f2bf(float f) {
    unsigned u = __builtin_bit_cast(unsigned, f);
    u += 0x7FFFu + ((u >> 16) & 1u);   // round-to-nearest-even
    return (unsigned short)(u >> 16);
}

__device__ __forceinline__ bf16x8 pack8(float4 a, float4 b) {
    union { bf16x8 v; unsigned short s[8]; } r;
    r.s[0] = f2bf(a.x); r.s[1] = f2bf(a.y); r.s[2] = f2bf(a.z); r.s[3] = f2bf(a.w);
    r.s[4] = f2bf(b.x); r.s[5] = f2bf(b.y); r.s[6] = f2bf(b.z); r.s[7] = f2bf(b.w);
    return r.v;
}

// ---------------------------------------------------------------------------
// Kernel 1: bucket tokens by pid, build tile worklist in workspace.
// meta layout (ints): [0]=n_tiles, [16..143]=tile_pid, [144..271]=tile_off,
//                     [272..399]=tile_len, [512..512+NTOK)=bucket (token ids)
// ---------------------------------------------------------------------------
__global__ void bucket_kernel(const int* __restrict__ pids, int* __restrict__ meta) {
    __shared__ int counts[NP];
    __shared__ int cursor[NP];
    int tid = threadIdx.x;
    if (tid < NP) counts[tid] = 0;
    __syncthreads();
    for (int i = tid; i < NTOK; i += 256)
        atomicAdd(&counts[pids[i] & (NP - 1)], 1);
    __syncthreads();
    if (tid == 0) {
        int acc = 0, nt = 0;
        for (int p = 0; p < NP; ++p) {
            int c = counts[p];
            cursor[p] = acc;
            for (int t = 0; t < c; t += TM) {
                meta[16 + nt]  = p;
                meta[144 + nt] = acc + t;
                meta[272 + nt] = (c - t < TM) ? (c - t) : TM;
                ++nt;
            }
            acc += c;
        }
        meta[0] = nt;
    }
    __syncthreads();
    int* bucket = meta + 512;
    for (int i = tid; i < NTOK; i += 256) {
        int p = pids[i] & (NP - 1);
        int pos = atomicAdd(&cursor[p], 1);
        bucket[pos] = i;
    }
}

// ---------------------------------------------------------------------------
// Kernel 2: partial H. grid = MT*KS blocks; block (tile, ks) computes
// Hpart[ks][tile] (64x64 fp32) = Xtile[:, ks*KW:(ks+1)*KW] @ U[p][slice].
// X A-fragments loaded directly global->reg (no LDS); U staged transposed.
// Wave w owns rows w*16..w*16+15 x all 64 cols.
// ---------------------------------------------------------------------------
__global__ __launch_bounds__(256, 4) void h_kernel(
    const float* __restrict__ x, const float* __restrict__ U,
    const int* __restrict__ meta, float* __restrict__ Hpart)
{
    __shared__ __align__(16) unsigned short Us[RANK][LDSTR];
    __shared__ int toks[TM];

    int tile = blockIdx.x >> 3;   // KS = 8
    int ks   = blockIdx.x & 7;
    int nt = meta[0];
    if (tile >= nt) return;
    int p   = meta[16 + tile];
    int off = meta[144 + tile];
    int len = meta[272 + tile];

    int tid  = threadIdx.x;
    int lane = tid & 63;
    int w    = tid >> 6;
    int l15  = lane & 15;
    int l4   = lane >> 4;

    const int* bucket = meta + 512;
    if (tid < TM) toks[tid] = (tid < len) ? bucket[off + tid] : -1;
    __syncthreads();

    int myrow = w * 16 + l15;          // token row this lane's A-frag covers
    int t = toks[myrow];
    bool valid = (t >= 0);
    const float* xrow = x + (size_t)(valid ? t : 0) * D_IN;

    const float* Up = U + (size_t)p * D_IN * RANK;

    f32x4 acc[4] = {};                 // 4 ni blocks of 16 cols

    int kbeg = ks * KW;
    for (int kc = kbeg; kc < kbeg + KW; kc += BK) {
        // --- A-frag global loads first (latency hides under U staging) ---
        float4 u0a{0,0,0,0}, u0b{0,0,0,0}, u1a{0,0,0,0}, u1b{0,0,0,0};
        if (valid) {
            const float* xp = xrow + kc + l4 * 8;
            u0a = *reinterpret_cast<const float4*>(xp);
            u0b = *reinterpret_cast<const float4*>(xp + 4);
            u1a = *reinterpret_cast<const float4*>(xp + 32);
            u1b = *reinterpret_cast<const float4*>(xp + 36);
        }
        // --- stage U transposed: Us[r][kk] = U[p][kc+kk][r] ---
        {
            int kk = tid >> 2;          // 0..63
            int q  = (tid & 3) * 16;    // r quarter
            const float* up = Up + (size_t)(kc + kk) * RANK + q;
#pragma unroll
            for (int i = 0; i < 4; ++i) {
                float4 v = *reinterpret_cast<const float4*>(up + i * 4);
                int r = q + i * 4;
                Us[r + 0][kk] = f2bf(v.x);
                Us[r + 1][kk] = f2bf(v.y);
                Us[r + 2][kk] = f2bf(v.z);
                Us[r + 3][kk] = f2bf(v.w);
            }
        }
        __syncthreads();

        bf16x8 a0 = pack8(u0a, u0b);   // k2 = 0
        bf16x8 a1 = pack8(u1a, u1b);   // k2 = 1
#pragma unroll
        for (int k2 = 0; k2 < 2; ++k2) {
            int kof = k2 * 32 + l4 * 8;
            bf16x8 a = k2 ? a1 : a0;
#pragma unroll
            for (int ni = 0; ni < 4; ++ni) {
                bf16x8 b = *reinterpret_cast<const bf16x8*>(&Us[ni * 16 + l15][kof]);
                acc[ni] = __builtin_amdgcn_mfma_f32_16x16x32_bf16(a, b, acc[ni], 0, 0, 0);
            }
        }
        __syncthreads();
    }

    // write partial H fp32; C/D layout: col=lane&15, row=(lane>>4)*4+reg
    float* hp = Hpart + ((size_t)ks * MT + tile) * (TM * RANK);
#pragma unroll
    for (int ni = 0; ni < 4; ++ni)
#pragma unroll
        for (int j = 0; j < 4; ++j) {
            int row = w * 16 + l4 * 4 + j;
            int col = ni * 16 + l15;
            hp[row * RANK + col] = acc[ni][j];
        }
}

// ---------------------------------------------------------------------------
// Kernel 3: reduce KS partials -> compact bf16 H [tile][64][64] row-major.
// grid = 2*MT blocks; block (tile, half) handles 32 rows.
// ---------------------------------------------------------------------------
__global__ __launch_bounds__(256, 4) void hsum_kernel(
    const int* __restrict__ meta, const float* __restrict__ Hpart,
    unsigned short* __restrict__ Hbf)
{
    int tile = blockIdx.x >> 1;
    int half = blockIdx.x & 1;
    if (tile >= meta[0]) return;
    int e = half * 2048 + threadIdx.x * 8;   // elem index in 64x64 tile

    f32x4 s0 = {}, s1 = {};
#pragma unroll
    for (int ks = 0; ks < KS; ++ks) {
        const f32x4* p = reinterpret_cast<const f32x4*>(
            &Hpart[((size_t)ks * MT + tile) * (TM * RANK) + e]);
        s0 += p[0];
        s1 += p[1];
    }
    union { int4 i4; unsigned short s[8]; } o;
#pragma unroll
    for (int j = 0; j < 4; ++j) { o.s[j] = f2bf(s0[j]); o.s[4 + j] = f2bf(s1[j]); }
    *reinterpret_cast<int4*>(&Hbf[(size_t)tile * (TM * RANK) + e]) = o.i4;
}

// ---------------------------------------------------------------------------
// Kernel 4: O = H @ V[p] + bias for one (tile, 128-col chunk).
// grid = MT * OSPLIT. H A-frags direct from global bf16 (L2-resident);
// V staged transposed in LDS. Wave w owns rows w*16..w*16+15 x 128 cols.
// ---------------------------------------------------------------------------
__global__ __launch_bounds__(256, 4) void o_kernel(
    const float* __restrict__ V, const float* __restrict__ bias,
    const int* __restrict__ meta, const unsigned short* __restrict__ Hbf,
    float* __restrict__ out)
{
    __shared__ __align__(16) unsigned short Vs[OW][LDSTR];
    __shared__ int toks[TM];

    int tile = blockIdx.x >> 3;   // OSPLIT = 8
    int oc   = (blockIdx.x & 7) * OW;
    int nt = meta[0];
    if (tile >= nt) return;
    int p   = meta[16 + tile];
    int off = meta[144 + tile];
    int len = meta[272 + tile];

    int tid  = threadIdx.x;
    int lane = tid & 63;
    int w    = tid >> 6;
    int l15  = lane & 15;
    int l4   = lane >> 4;

    const int* bucket = meta + 512;
    if (tid < TM) toks[tid] = (tid < len) ? bucket[off + tid] : -1;

    // stage V transposed: Vs[o][r] = V[p][r][oc+o]
    const float* Vp = V + (size_t)p * RANK * D_OUT;
    {
        int o4 = (tid & 31) * 4;
        int rb = tid >> 5;          // 0..7
#pragma unroll
        for (int pass = 0; pass < 8; ++pass) {
            int r = pass * 8 + rb;
            float4 v = *reinterpret_cast<const float4*>(&Vp[(size_t)r * D_OUT + oc + o4]);
            Vs[o4 + 0][r] = f2bf(v.x);
            Vs[o4 + 1][r] = f2bf(v.y);
            Vs[o4 + 2][r] = f2bf(v.z);
            Vs[o4 + 3][r] = f2bf(v.w);
        }
    }
    __syncthreads();

    const unsigned short* Hrow = Hbf + (size_t)tile * (TM * RANK) + (w * 16 + l15) * RANK;

    f32x4 acc[8] = {};
#pragma unroll
    for (int k2 = 0; k2 < 2; ++k2) {
        int kof = k2 * 32 + l4 * 8;
        bf16x8 a = *reinterpret_cast<const bf16x8*>(Hrow + kof);
#pragma unroll
        for (int ni = 0; ni < 8; ++ni) {
            bf16x8 b = *reinterpret_cast<const bf16x8*>(&Vs[ni * 16 + l15][kof]);
            acc[ni] = __builtin_amdgcn_mfma_f32_16x16x32_bf16(a, b, acc[ni], 0, 0, 0);
        }
    }

    // bias + scatter store
    int r0 = w * 16 + l4 * 4;
    int t0 = toks[r0 + 0], t1 = toks[r0 + 1], t2 = toks[r0 + 2], t3 = toks[r0 + 3];
#pragma unroll
    for (int ni = 0; ni < 8; ++ni) {
        int col = oc + ni * 16 + l15;
        float bv = bias[col];
        if (r0 + 0 < len) out[(size_t)t0 * D_OUT + col] = acc[ni][0] + bv;
        if (r0 + 1 < len) out[(size_t)t1 * D_OUT + col] = acc[ni][1] + bv;
        if (r0 + 2 < len) out[(size_t)t2 * D_OUT + col] = acc[ni][2] + bv;
        if (r0 + 3 < len) out[(size_t)t3 * D_OUT + col] = acc[ni][3] + bv;
    }
}

extern "C" void kernel_launch(void* const* d_in, const int* in_sizes, int n_in,
                              void* d_out, int out_size, void* d_ws, size_t ws_size,
                              hipStream_t stream) {
    const float* x    = (const float*)d_in[0];
    const int*   pids = (const int*)d_in[1];
    const float* U    = (const float*)d_in[2];
    const float* V    = (const float*)d_in[3];
    const float* bias = (const float*)d_in[4];
    float* out = (float*)d_out;

    int* meta = (int*)d_ws;                                       // 64 KB
    unsigned short* Hbf = (unsigned short*)((char*)d_ws + 65536); // 1 MB
    float* Hpart = (float*)((char*)d_ws + 65536
                            + (size_t)MT * TM * RANK * sizeof(unsigned short)); // 16 MB

    bucket_kernel<<<1, 256, 0, stream>>>(pids, meta);
    h_kernel<<<MT * KS, 256, 0, stream>>>(x, U, meta, Hpart);
    hsum_kernel<<<MT * 2, 256, 0, stream>>>(meta, Hpart, Hbf);
    o_kernel<<<MT * OSPLIT, 256, 0, stream>>>(V, bias, meta, Hbf, out);
}

// Round 4
// 42.335 us; speedup vs baseline: 2.3570x; 1.2337x over previous
//
#include <hip/hip_runtime.h>
#include <hip/hip_bf16.h>

#define NP     64     // partitions
#define D_IN   1024
#define RANK   64
#define D_OUT  1024
#define NTOK   4096
#define TM     64     // tokens per tile
#define BK     64     // K chunk for h step
#define MT     128    // max tiles
#define KS     8      // K-split for h_kernel
#define KW     (D_IN / KS)   // 128
#define OW     128    // D_OUT cols per o-block
#define OSPLIT (D_OUT / OW)  // 8
#define LDSTR  72     // LDS row stride in bf16 elems (144B, 16B-aligned, bank-spread)

typedef __bf16 bf16x8 __attribute__((ext_vector_type(8)));
typedef float  f32x4  __attribute__((ext_vector_type(4)));

__device__ __forceinline__ unsigned short f2bf(float f) {
    unsigned u = __builtin_bit_cast(unsigned, f);
    u += 0x7FFFu + ((u >> 16) & 1u);   // round-to-nearest-even
    return (unsigned short)(u >> 16);
}
__device__ __forceinline__ float bf2f(unsigned short s) {
    unsigned u = (unsigned)s << 16;
    return __builtin_bit_cast(float, u);
}
__device__ __forceinline__ bf16x8 pack8(float4 a, float4 b) {
    union { bf16x8 v; unsigned short s[8]; } r;
    r.s[0] = f2bf(a.x); r.s[1] = f2bf(a.y); r.s[2] = f2bf(a.z); r.s[3] = f2bf(a.w);
    r.s[4] = f2bf(b.x); r.s[5] = f2bf(b.y); r.s[6] = f2bf(b.z); r.s[7] = f2bf(b.w);
    return r.v;
}

// ---------------------------------------------------------------------------
// Kernel 1: bucket tokens by pid, build tile worklist. Wave-parallel scans.
// meta (ints): [0]=n_tiles, [16..]=tile_pid, [144..]=tile_off, [272..]=tile_len,
//              [512..512+NTOK)=bucket (token ids)
// ---------------------------------------------------------------------------
__global__ void bucket_kernel(const int* __restrict__ pids, int* __restrict__ meta) {
    __shared__ int counts[NP];
    __shared__ int cursor[NP];
    int tid = threadIdx.x;
    if (tid < NP) counts[tid] = 0;
    __syncthreads();
    for (int i = tid; i < NTOK; i += 256)
        atomicAdd(&counts[pids[i] & (NP - 1)], 1);
    __syncthreads();
    if (tid < 64) {
        int c = counts[tid];
        int ntp = (c + TM - 1) >> 6;     // tiles for this partition
        int sc = c, st = ntp;            // inclusive scans via shfl
        for (int d = 1; d < 64; d <<= 1) {
            int vc = __shfl_up(sc, d);
            int vt = __shfl_up(st, d);
            if (tid >= d) { sc += vc; st += vt; }
        }
        int cbase = sc - c;              // exclusive prefix (token offset)
        int tb    = st - ntp;            // exclusive prefix (tile index)
        cursor[tid] = cbase;
        for (int t = 0; t < ntp; ++t) {
            int idx = tb + t;
            meta[16 + idx]  = tid;
            meta[144 + idx] = cbase + t * TM;
            int rem = c - t * TM;
            meta[272 + idx] = rem < TM ? rem : TM;
        }
        if (tid == 63) meta[0] = st;
    }
    __syncthreads();
    int* bucket = meta + 512;
    for (int i = tid; i < NTOK; i += 256) {
        int p = pids[i] & (NP - 1);
        int pos = atomicAdd(&cursor[p], 1);
        bucket[pos] = i;
    }
}

// ---------------------------------------------------------------------------
// Kernel 2: partial H (bf16). grid = MT*KS; block (tile,ks) computes
// Hpart[ks][tile] (64x64) = Xtile[:, ks*KW..] @ U[p][slice].
// X A-frags direct global->reg (both chunks hoisted); U staged transposed.
// Wave w owns rows w*16..w*16+15 x all 64 cols.
// ---------------------------------------------------------------------------
__global__ __launch_bounds__(256, 4) void h_kernel(
    const float* __restrict__ x, const float* __restrict__ U,
    const int* __restrict__ meta, unsigned short* __restrict__ Hpart)
{
    __shared__ __align__(16) unsigned short Us[RANK][LDSTR];
    __shared__ int toks[TM];

    int tile = blockIdx.x >> 3;   // KS = 8
    int ks   = blockIdx.x & 7;
    int nt = meta[0];
    if (tile >= nt) return;
    int p   = meta[16 + tile];
    int off = meta[144 + tile];
    int len = meta[272 + tile];

    int tid  = threadIdx.x;
    int lane = tid & 63;
    int w    = tid >> 6;
    int l15  = lane & 15;
    int l4   = lane >> 4;

    const int* bucket = meta + 512;
    if (tid < TM) toks[tid] = (tid < len) ? bucket[off + tid] : -1;
    __syncthreads();

    int myrow = w * 16 + l15;
    int t = toks[myrow];
    bool valid = (t >= 0);
    const float* xrow = x + (size_t)(valid ? t : 0) * D_IN;
    const float* Up = U + (size_t)p * D_IN * RANK;

    int kbeg = ks * KW;

    // hoist ALL X loads for both 64-chunks (one vmcnt drain at first barrier)
    float4 z{0,0,0,0};
    float4 c0a=z,c0b=z,c0c=z,c0d=z,c1a=z,c1b=z,c1c=z,c1d=z;
    if (valid) {
        const float* xp = xrow + kbeg + l4 * 8;
        c0a = *reinterpret_cast<const float4*>(xp);
        c0b = *reinterpret_cast<const float4*>(xp + 4);
        c0c = *reinterpret_cast<const float4*>(xp + 32);
        c0d = *reinterpret_cast<const float4*>(xp + 36);
        c1a = *reinterpret_cast<const float4*>(xp + 64);
        c1b = *reinterpret_cast<const float4*>(xp + 68);
        c1c = *reinterpret_cast<const float4*>(xp + 96);
        c1d = *reinterpret_cast<const float4*>(xp + 100);
    }

    f32x4 acc[4] = {};

    // ---- chunk 0 ----
    {
        int kk = tid >> 2;
        int q  = (tid & 3) * 16;
        const float* up = Up + (size_t)(kbeg + kk) * RANK + q;
#pragma unroll
        for (int i = 0; i < 4; ++i) {
            float4 v = *reinterpret_cast<const float4*>(up + i * 4);
            int r = q + i * 4;
            Us[r + 0][kk] = f2bf(v.x);
            Us[r + 1][kk] = f2bf(v.y);
            Us[r + 2][kk] = f2bf(v.z);
            Us[r + 3][kk] = f2bf(v.w);
        }
    }
    __syncthreads();
    {
        bf16x8 a0 = pack8(c0a, c0b);
        bf16x8 a1 = pack8(c0c, c0d);
#pragma unroll
        for (int k2 = 0; k2 < 2; ++k2) {
            int kof = k2 * 32 + l4 * 8;
            bf16x8 a = k2 ? a1 : a0;
#pragma unroll
            for (int ni = 0; ni < 4; ++ni) {
                bf16x8 b = *reinterpret_cast<const bf16x8*>(&Us[ni * 16 + l15][kof]);
                acc[ni] = __builtin_amdgcn_mfma_f32_16x16x32_bf16(a, b, acc[ni], 0, 0, 0);
            }
        }
    }
    __syncthreads();
    // ---- chunk 1 ----
    {
        int kk = tid >> 2;
        int q  = (tid & 3) * 16;
        const float* up = Up + (size_t)(kbeg + BK + kk) * RANK + q;
#pragma unroll
        for (int i = 0; i < 4; ++i) {
            float4 v = *reinterpret_cast<const float4*>(up + i * 4);
            int r = q + i * 4;
            Us[r + 0][kk] = f2bf(v.x);
            Us[r + 1][kk] = f2bf(v.y);
            Us[r + 2][kk] = f2bf(v.z);
            Us[r + 3][kk] = f2bf(v.w);
        }
    }
    __syncthreads();
    {
        bf16x8 a0 = pack8(c1a, c1b);
        bf16x8 a1 = pack8(c1c, c1d);
#pragma unroll
        for (int k2 = 0; k2 < 2; ++k2) {
            int kof = k2 * 32 + l4 * 8;
            bf16x8 a = k2 ? a1 : a0;
#pragma unroll
            for (int ni = 0; ni < 4; ++ni) {
                bf16x8 b = *reinterpret_cast<const bf16x8*>(&Us[ni * 16 + l15][kof]);
                acc[ni] = __builtin_amdgcn_mfma_f32_16x16x32_bf16(a, b, acc[ni], 0, 0, 0);
            }
        }
    }

    // write bf16 partial H; C/D layout: col=lane&15, row=(lane>>4)*4+reg
    unsigned short* hp = Hpart + ((size_t)ks * MT + tile) * (TM * RANK);
#pragma unroll
    for (int ni = 0; ni < 4; ++ni)
#pragma unroll
        for (int j = 0; j < 4; ++j) {
            int row = w * 16 + l4 * 4 + j;
            int col = ni * 16 + l15;
            hp[row * RANK + col] = f2bf(acc[ni][j]);
        }
}

// ---------------------------------------------------------------------------
// Kernel 3: reduce KS bf16 partials -> compact bf16 H [tile][64][64].
// grid = 2*MT; block (tile, half) handles 2048 elems, 8 per thread.
// ---------------------------------------------------------------------------
__global__ __launch_bounds__(256, 4) void hsum_kernel(
    const int* __restrict__ meta, const unsigned short* __restrict__ Hpart,
    unsigned short* __restrict__ Hbf)
{
    int tile = blockIdx.x >> 1;
    int half = blockIdx.x & 1;
    if (tile >= meta[0]) return;
    int e = half * 2048 + threadIdx.x * 8;

    float s[8] = {};
#pragma unroll
    for (int ks = 0; ks < KS; ++ks) {
        union { int4 i4; unsigned short u[8]; } v;
        v.i4 = *reinterpret_cast<const int4*>(
            &Hpart[((size_t)ks * MT + tile) * (TM * RANK) + e]);
#pragma unroll
        for (int j = 0; j < 8; ++j) s[j] += bf2f(v.u[j]);
    }
    union { int4 i4; unsigned short u[8]; } o;
#pragma unroll
    for (int j = 0; j < 8; ++j) o.u[j] = f2bf(s[j]);
    *reinterpret_cast<int4*>(&Hbf[(size_t)tile * (TM * RANK) + e]) = o.i4;
}

// ---------------------------------------------------------------------------
// Kernel 4: O = H @ V[p] + bias for one (tile, 128-col chunk). grid = MT*8.
// H A-frags direct from global bf16; V staged transposed in LDS.
// ---------------------------------------------------------------------------
__global__ __launch_bounds__(256, 4) void o_kernel(
    const float* __restrict__ V, const float* __restrict__ bias,
    const int* __restrict__ meta, const unsigned short* __restrict__ Hbf,
    float* __restrict__ out)
{
    __shared__ __align__(16) unsigned short Vs[OW][LDSTR];
    __shared__ int toks[TM];

    int tile = blockIdx.x >> 3;   // OSPLIT = 8
    int oc   = (blockIdx.x & 7) * OW;
    int nt = meta[0];
    if (tile >= nt) return;
    int p   = meta[16 + tile];
    int off = meta[144 + tile];
    int len = meta[272 + tile];

    int tid  = threadIdx.x;
    int lane = tid & 63;
    int w    = tid >> 6;
    int l15  = lane & 15;
    int l4   = lane >> 4;

    const int* bucket = meta + 512;
    if (tid < TM) toks[tid] = (tid < len) ? bucket[off + tid] : -1;

    // stage V transposed: Vs[o][r] = V[p][r][oc+o]
    const float* Vp = V + (size_t)p * RANK * D_OUT;
    {
        int o4 = (tid & 31) * 4;
        int rb = tid >> 5;          // 0..7
#pragma unroll
        for (int pass = 0; pass < 8; ++pass) {
            int r = pass * 8 + rb;
            float4 v = *reinterpret_cast<const float4*>(&Vp[(size_t)r * D_OUT + oc + o4]);
            Vs[o4 + 0][r] = f2bf(v.x);
            Vs[o4 + 1][r] = f2bf(v.y);
            Vs[o4 + 2][r] = f2bf(v.z);
            Vs[o4 + 3][r] = f2bf(v.w);
        }
    }
    __syncthreads();

    const unsigned short* Hrow = Hbf + (size_t)tile * (TM * RANK) + (w * 16 + l15) * RANK;

    f32x4 acc[8] = {};
#pragma unroll
    for (int k2 = 0; k2 < 2; ++k2) {
        int kof = k2 * 32 + l4 * 8;
        bf16x8 a = *reinterpret_cast<const bf16x8*>(Hrow + kof);
#pragma unroll
        for (int ni = 0; ni < 8; ++ni) {
            bf16x8 b = *reinterpret_cast<const bf16x8*>(&Vs[ni * 16 + l15][kof]);
            acc[ni] = __builtin_amdgcn_mfma_f32_16x16x32_bf16(a, b, acc[ni], 0, 0, 0);
        }
    }

    // bias + scatter store
    int r0 = w * 16 + l4 * 4;
    int t0 = toks[r0 + 0], t1 = toks[r0 + 1], t2 = toks[r0 + 2], t3 = toks[r0 + 3];
#pragma unroll
    for (int ni = 0; ni < 8; ++ni) {
        int col = oc + ni * 16 + l15;
        float bv = bias[col];
        if (r0 + 0 < len) out[(size_t)t0 * D_OUT + col] = acc[ni][0] + bv;
        if (r0 + 1 < len) out[(size_t)t1 * D_OUT + col] = acc[ni][1] + bv;
        if (r0 + 2 < len) out[(size_t)t2 * D_OUT + col] = acc[ni][2] + bv;
        if (r0 + 3 < len) out[(size_t)t3 * D_OUT + col] = acc[ni][3] + bv;
    }
}

extern "C" void kernel_launch(void* const* d_in, const int* in_sizes, int n_in,
                              void* d_out, int out_size, void* d_ws, size_t ws_size,
                              hipStream_t stream) {
    const float* x    = (const float*)d_in[0];
    const int*   pids = (const int*)d_in[1];
    const float* U    = (const float*)d_in[2];
    const float* V    = (const float*)d_in[3];
    const float* bias = (const float*)d_in[4];
    float* out = (float*)d_out;

    int* meta = (int*)d_ws;                                       // 64 KB
    unsigned short* Hbf = (unsigned short*)((char*)d_ws + 65536); // 1 MB
    unsigned short* Hpart = (unsigned short*)((char*)d_ws + 65536
                            + (size_t)MT * TM * RANK * sizeof(unsigned short)); // 8 MB

    bucket_kernel<<<1, 256, 0, stream>>>(pids, meta);
    h_kernel<<<MT * KS, 256, 0, stream>>>(x, U, meta, Hpart);
    hsum_kernel<<<MT * 2, 256, 0, stream>>>(meta, Hpart, Hbf);
    o_kernel<<<MT * OSPLIT, 256, 0, stream>>>(V, bias, meta, Hbf, out);
}